// Round 2
// baseline (489.152 us; speedup 1.0000x reference)
//
#include <hip/hip_runtime.h>
#include <hip/hip_bf16.h>
#include <cmath>

#define BATCH     16384
#define CTX       10
#define NSENSE    8
#define VEC_DIM   128
#define XCOLS     (2 + CTX)

// 16 lanes per batch element, 8 dims/lane (2x float4 = 16 B loads).
// Each 16-lane group reads a contiguous 512 B row segment -> perfectly
// coalesced; butterflies are 4 steps within width-16 groups.
__global__ __launch_bounds__(256) void SenseEmbedding_40295383171457_kernel(
    const int*   __restrict__ x,     // [BATCH, 12]
    const float* __restrict__ Wg,    // [VOCAB, 128]
    const float* __restrict__ Ws,    // [VOCAB, 8, 128]
    float*       __restrict__ out)   // [BATCH, 1]
{
    const int gtid = blockIdx.x * blockDim.x + threadIdx.x;
    const int elem = gtid >> 4;          // 16 lanes per element
    const int sub  = gtid & 15;
    if (elem >= BATCH) return;

    const int* xr = x + elem * XCOLS;
    const int w0 = xr[0];
    const int w1 = xr[1];
    const int off = sub * 8;             // this lane's 8-float slice of a row

    // ---- sum_context over 10 gathered W_g rows ----
    float4 c0 = make_float4(0.f, 0.f, 0.f, 0.f);
    float4 c1 = make_float4(0.f, 0.f, 0.f, 0.f);
    #pragma unroll
    for (int c = 0; c < CTX; ++c) {
        const float* row = Wg + (size_t)xr[2 + c] * VEC_DIM + off;
        const float4 a = *reinterpret_cast<const float4*>(row);
        const float4 b = *reinterpret_cast<const float4*>(row + 4);
        c0.x += a.x; c0.y += a.y; c0.z += a.z; c0.w += a.w;
        c1.x += b.x; c1.y += b.y; c1.z += b.z; c1.w += b.w;
    }

    // ---- scores[k] = <W_s[w0,k,:], sum_context> ----
    const float* srow = Ws + (size_t)w0 * (NSENSE * VEC_DIM);
    float scores[NSENSE];
    #pragma unroll
    for (int k = 0; k < NSENSE; ++k) {
        const float* r = srow + k * VEC_DIM + off;
        const float4 a = *reinterpret_cast<const float4*>(r);
        const float4 b = *reinterpret_cast<const float4*>(r + 4);
        float p = a.x * c0.x + a.y * c0.y + a.z * c0.z + a.w * c0.w
                + b.x * c1.x + b.y * c1.y + b.z * c1.z + b.w * c1.w;
        #pragma unroll
        for (int s = 8; s > 0; s >>= 1)
            p += __shfl_xor(p, s, 16);   // reduce within the 16-lane group
        scores[k] = p;
    }

    // ---- argmax (first-occurrence, matches jnp.argmax) ----
    int   best = 0;
    float bv   = scores[0];
    #pragma unroll
    for (int k = 1; k < NSENSE; ++k) {
        if (scores[k] > bv) { bv = scores[k]; best = k; }
    }

    // ---- dot(chosen, W_g[w1]) ----
    const float* ch = srow + best * VEC_DIM + off;   // L1/L2-hot re-read
    const float4 ca = *reinterpret_cast<const float4*>(ch);
    const float4 cb = *reinterpret_cast<const float4*>(ch + 4);
    const float* tg = Wg + (size_t)w1 * VEC_DIM + off;
    const float4 ta = *reinterpret_cast<const float4*>(tg);
    const float4 tb = *reinterpret_cast<const float4*>(tg + 4);
    float d = ca.x * ta.x + ca.y * ta.y + ca.z * ta.z + ca.w * ta.w
            + cb.x * tb.x + cb.y * tb.y + cb.z * tb.z + cb.w * tb.w;
    #pragma unroll
    for (int s = 8; s > 0; s >>= 1)
        d += __shfl_xor(d, s, 16);

    if (sub == 0) {
        out[elem] = 1.f / (1.f + expf(-d));
    }
}

extern "C" void kernel_launch(void* const* d_in, const int* in_sizes, int n_in,
                              void* d_out, int out_size, void* d_ws, size_t ws_size,
                              hipStream_t stream) {
    const int*   x  = (const int*)  d_in[0];
    const float* Wg = (const float*)d_in[1];
    const float* Ws = (const float*)d_in[2];
    float*       out = (float*)d_out;

    // 16 elements per 256-thread block.
    const int elems_per_block = 256 / 16;
    const int grid = (BATCH + elems_per_block - 1) / elems_per_block;
    SenseEmbedding_40295383171457_kernel<<<grid, 256, 0, stream>>>(x, Wg, Ws, out);
}

// Round 3
// 483.864 us; speedup vs baseline: 1.0109x; 1.0109x over previous
//
#include <hip/hip_runtime.h>
#include <hip/hip_bf16.h>
#include <cmath>

#define BATCH     16384
#define CTX       10
#define NSENSE    8
#define VEC_DIM   128
#define XCOLS     (2 + CTX)

// 16 lanes per batch element, 8 dims/lane (2x float4 = 16 B loads).
// Chain: x(int4 x3) -> {context rows, sense rows, target row} all independent
// -> p_k (scores) + q_k (target dots) -> reduce p -> argmax -> select q_best
// -> reduce q -> sigmoid. Only 3 serial memory levels (was 4: dependent
// chosen-row reload removed by precomputing q_k for all k).
__global__ __launch_bounds__(256) void SenseEmbedding_40295383171457_kernel(
    const int*   __restrict__ x,     // [BATCH, 12]
    const float* __restrict__ Wg,    // [VOCAB, 128]
    const float* __restrict__ Ws,    // [VOCAB, 8, 128]
    float*       __restrict__ out)   // [BATCH, 1]
{
    const int gtid = blockIdx.x * blockDim.x + threadIdx.x;
    const int elem = gtid >> 4;          // 16 lanes per element
    const int sub  = gtid & 15;
    if (elem >= BATCH) return;

    // x row is 48 B, 16 B-aligned -> 3 int4 loads instead of 12 scalar ints.
    const int4* xr4 = reinterpret_cast<const int4*>(x + elem * XCOLS);
    const int4 xa = xr4[0];   // w0, w1, ctx0, ctx1
    const int4 xb = xr4[1];   // ctx2..ctx5
    const int4 xc = xr4[2];   // ctx6..ctx9
    const int off = sub * 8;  // this lane's 8-float slice of a row

    // Target row (independent of everything else; issues early).
    const float* tgt = Wg + (size_t)xa.y * VEC_DIM + off;
    const float4 t0 = *reinterpret_cast<const float4*>(tgt);
    const float4 t1 = *reinterpret_cast<const float4*>(tgt + 4);

    // ---- sum_context over 10 gathered W_g rows ----
    const int cidx[CTX] = {xa.z, xa.w, xb.x, xb.y, xb.z, xb.w,
                           xc.x, xc.y, xc.z, xc.w};
    float4 c0 = make_float4(0.f, 0.f, 0.f, 0.f);
    float4 c1 = make_float4(0.f, 0.f, 0.f, 0.f);
    #pragma unroll
    for (int c = 0; c < CTX; ++c) {
        const float* row = Wg + (size_t)cidx[c] * VEC_DIM + off;
        const float4 a = *reinterpret_cast<const float4*>(row);
        const float4 b = *reinterpret_cast<const float4*>(row + 4);
        c0.x += a.x; c0.y += a.y; c0.z += a.z; c0.w += a.w;
        c1.x += b.x; c1.y += b.y; c1.z += b.z; c1.w += b.w;
    }

    // ---- per-sense: score partial p_k AND target-dot partial q_k ----
    const float* srow = Ws + (size_t)xa.x * (NSENSE * VEC_DIM);
    float p[NSENSE], q[NSENSE];
    #pragma unroll
    for (int k = 0; k < NSENSE; ++k) {
        const float* r = srow + k * VEC_DIM + off;
        const float4 a = *reinterpret_cast<const float4*>(r);
        const float4 b = *reinterpret_cast<const float4*>(r + 4);
        p[k] = a.x * c0.x + a.y * c0.y + a.z * c0.z + a.w * c0.w
             + b.x * c1.x + b.y * c1.y + b.z * c1.z + b.w * c1.w;
        q[k] = a.x * t0.x + a.y * t0.y + a.z * t0.z + a.w * t0.w
             + b.x * t1.x + b.y * t1.y + b.z * t1.z + b.w * t1.w;
    }

    // ---- reduce scores within the 16-lane group ----
    #pragma unroll
    for (int k = 0; k < NSENSE; ++k) {
        float v = p[k];
        #pragma unroll
        for (int s = 8; s > 0; s >>= 1)
            v += __shfl_xor(v, s, 16);
        p[k] = v;
    }

    // ---- argmax (first-occurrence, group-uniform) ----
    int   best = 0;
    float bv   = p[0];
    #pragma unroll
    for (int k = 1; k < NSENSE; ++k) {
        if (p[k] > bv) { bv = p[k]; best = k; }
    }

    // ---- select q_best (uniform index -> cndmask chain), reduce, sigmoid ----
    float qb = q[0];
    #pragma unroll
    for (int k = 1; k < NSENSE; ++k)
        qb = (best == k) ? q[k] : qb;
    #pragma unroll
    for (int s = 8; s > 0; s >>= 1)
        qb += __shfl_xor(qb, s, 16);

    if (sub == 0) {
        out[elem] = 1.f / (1.f + expf(-qb));
    }
}

extern "C" void kernel_launch(void* const* d_in, const int* in_sizes, int n_in,
                              void* d_out, int out_size, void* d_ws, size_t ws_size,
                              hipStream_t stream) {
    const int*   x  = (const int*)  d_in[0];
    const float* Wg = (const float*)d_in[1];
    const float* Ws = (const float*)d_in[2];
    float*       out = (float*)d_out;

    const int elems_per_block = 256 / 16;
    const int grid = (BATCH + elems_per_block - 1) / elems_per_block;
    SenseEmbedding_40295383171457_kernel<<<grid, 256, 0, stream>>>(x, Wg, Ws, out);
}